// Round 2
// baseline (7200.490 us; speedup 1.0000x reference)
//
#include <hip/hip_runtime.h>

#define DEVINL __device__ __forceinline__

constexpr int J_ = 3000;   // frames
constexpr int I_ = 2049;   // freq bins
constexpr int K_ = 8;      // NMF bases
constexpr int NITER = 30;
constexpr float EPS = 1e-20f;  // NMF_EPS == IP_EPS
constexpr int JH = J_ / 2;                 // 1500 complex-pairs per row
constexpr int NPAIR = (JH + 255) / 256;    // 6 register-resident pair-iters
constexpr int TJ = 256;
constexpr int NJT = (J_ + TJ - 1) / TJ;    // 12

DEVINL float waveRed(float v) {
#pragma unroll
  for (int off = 32; off > 0; off >>= 1) v += __shfl_xor(v, off, 64);
  return v;
}

// ---------------- init: T -> (n,i,k) layout; V copy; W = identity ----------------
__global__ void k_init(const float* __restrict__ Tin, const float* __restrict__ Vin,
                       float* __restrict__ T, float2* __restrict__ V2, float2* __restrict__ W2) {
  int idx = blockIdx.x * 256 + threadIdx.x;
  if (idx < I_ * K_ * 2) {
    int n = idx & 1, rem = idx >> 1;  // idx = (i*K + k)*2 + n
    int k = rem & 7, i = rem >> 3;
    T[n * I_ * K_ + i * K_ + k] = Tin[idx];
  }
  if (idx < K_ * J_) V2[idx] = ((const float2*)Vin)[idx];
  if (idx < I_) {
    W2[idx * 4 + 0] = make_float2(1.f, 0.f);
    W2[idx * 4 + 1] = make_float2(0.f, 0.f);
    W2[idx * 4 + 2] = make_float2(0.f, 0.f);
    W2[idx * 4 + 3] = make_float2(1.f, 0.f);
  }
}

// ------------- transpose X (M,J,I) cplx -> Xt (M,I,J) cplx -------------
__global__ __launch_bounds__(256) void k_transpose(const float2* __restrict__ X, float2* __restrict__ Xt) {
  __shared__ float2 tile[32][33];
  int m = blockIdx.z;
  int i0 = blockIdx.x * 32, j0 = blockIdx.y * 32;
  int tx = threadIdx.x & 31, ty = threadIdx.x >> 5;
  for (int r = ty; r < 32; r += 8) {
    int j = j0 + r, i = i0 + tx;
    if (i < I_ && j < J_) tile[r][tx] = X[((size_t)m * J_ + j) * I_ + i];
  }
  __syncthreads();
  for (int r = ty; r < 32; r += 8) {
    int i = i0 + r, j = j0 + tx;
    if (i < I_ && j < J_) Xt[((size_t)m * I_ + i) * J_ + j] = tile[tx][r];
  }
}

// ============ fused kernel: [C phase: D + IP -> W_new] + [A phase: YdR + T update] ============
// DO_C=false,DO_A=true  : passA for iteration 0 (W read as-is)
// DO_C=true, DO_A=true  : passC(t) fused with passA(t+1) — X streamed ONCE
// DO_C=true, DO_A=false : final passC (iteration 29)
template <bool DO_C, bool DO_A>
__global__ __launch_bounds__(256) void k_CA(const float4* __restrict__ Xt4,  // (2,I,JH) float4 = 2 cplx
                                            float2* __restrict__ W2,
                                            float* __restrict__ T,           // (2,I,K)
                                            const float4* __restrict__ V4,   // (K,JH) float4 = both srcs, 2 j
                                            float2* __restrict__ YdR2) {     // (2,I,JH)
  const int i = blockIdx.x, t = threadIdx.x;
  float T0[K_], T1[K_];
#pragma unroll
  for (int k = 0; k < K_; k++) {
    T0[k] = T[i * K_ + k];
    T1[k] = T[I_ * K_ + i * K_ + k];
  }
  const float4* x0r = Xt4 + (size_t)i * JH;
  const float4* x1r = Xt4 + (size_t)(I_ + i) * JH;

  float q00[2 * NPAIR], q11[2 * NPAIR], qre[2 * NPAIR], qim[2 * NPAIR];
  float R0[2 * NPAIR], R1[2 * NPAIR];
  float acc[8] = {};

#pragma unroll
  for (int l = 0; l < NPAIR; l++) {
    int j2 = t + l * 256;
    bool ok = j2 < JH;
    float4 x0 = ok ? x0r[j2] : make_float4(0.f, 0.f, 0.f, 0.f);
    float4 x1 = ok ? x1r[j2] : make_float4(0.f, 0.f, 0.f, 0.f);
    float n00a = x0.x * x0.x + x0.y * x0.y, n00b = x0.z * x0.z + x0.w * x0.w;
    float n11a = x1.x * x1.x + x1.y * x1.y, n11b = x1.z * x1.z + x1.w * x1.w;
    float crea = x0.x * x1.x + x0.y * x1.y, creb = x0.z * x1.z + x0.w * x1.w;
    float cima = x0.y * x1.x - x0.x * x1.y, cimb = x0.w * x1.z - x0.z * x1.w;
    q00[2 * l] = n00a; q00[2 * l + 1] = n00b;
    q11[2 * l] = n11a; q11[2 * l + 1] = n11b;
    qre[2 * l] = crea; qre[2 * l + 1] = creb;
    qim[2 * l] = cima; qim[2 * l + 1] = cimb;
    float r0a = 0.f, r0b = 0.f, r1a = 0.f, r1b = 0.f;
#pragma unroll
    for (int k = 0; k < K_; k++) {
      float4 vp = ok ? V4[(size_t)k * JH + j2] : make_float4(0.f, 0.f, 0.f, 0.f);
      r0a += T0[k] * vp.x; r1a += T1[k] * vp.y;
      r0b += T0[k] * vp.z; r1b += T1[k] * vp.w;
    }
    R0[2 * l] = r0a; R0[2 * l + 1] = r0b;
    R1[2 * l] = r1a; R1[2 * l + 1] = r1b;
    if (DO_C) {
      float i0a = 1.f / (r0a + EPS), i0b = 1.f / (r0b + EPS);
      float i1a = 1.f / (r1a + EPS), i1b = 1.f / (r1b + EPS);
      acc[0] += n00a * i0a + n00b * i0b;
      acc[1] += n11a * i0a + n11b * i0b;
      acc[2] += crea * i0a + creb * i0b;
      acc[3] += cima * i0a + cimb * i0b;
      acc[4] += n00a * i1a + n00b * i1b;
      acc[5] += n11a * i1a + n11b * i1b;
      acc[6] += crea * i1a + creb * i1b;
      acc[7] += cima * i1a + cimb * i1b;
    }
  }

  __shared__ float sred[4][32];
  __shared__ float sout[32];
  __shared__ float sbc[8];  // alpha,beta,gamma,delta per source
  const int wave = t >> 6, lane = t & 63;

  if constexpr (DO_C) {
#pragma unroll
    for (int q = 0; q < 8; q++) {
      float v = waveRed(acc[q]);
      if (lane == 0) sred[wave][q] = v;
    }
    __syncthreads();
    if (t < 8) sout[t] = sred[0][t] + sred[1][t] + sred[2][t] + sred[3][t];
    __syncthreads();
    if (t == 0) {
      const double Jinv = 1.0 / (double)J_;
      double D[2][4];
#pragma unroll
      for (int s2 = 0; s2 < 2; s2++) {
        D[s2][0] = (double)sout[s2 * 4 + 0] * Jinv + (double)EPS;
        D[s2][1] = (double)sout[s2 * 4 + 1] * Jinv + (double)EPS;
        D[s2][2] = (double)sout[s2 * 4 + 2] * Jinv;
        D[s2][3] = (double)sout[s2 * 4 + 3] * Jinv;
      }
      double Wd[2][2][2];
#pragma unroll
      for (int r = 0; r < 2; r++)
#pragma unroll
        for (int c = 0; c < 2; c++) {
          float2 w = W2[i * 4 + r * 2 + c];
          Wd[r][c][0] = w.x;
          Wd[r][c][1] = w.y;
        }
      for (int n2 = 0; n2 < 2; n2++) {
        double d00 = D[n2][0], d11 = D[n2][1], dre = D[n2][2], dim = D[n2][3];
        double A[2][2][2];
#pragma unroll
        for (int r = 0; r < 2; r++) {
          A[r][0][0] = Wd[r][0][0] * d00 + (Wd[r][1][0] * dre + Wd[r][1][1] * dim);
          A[r][0][1] = Wd[r][0][1] * d00 + (Wd[r][1][1] * dre - Wd[r][1][0] * dim);
          A[r][1][0] = Wd[r][1][0] * d11 + (Wd[r][0][0] * dre - Wd[r][0][1] * dim);
          A[r][1][1] = Wd[r][1][1] * d11 + (Wd[r][0][1] * dre + Wd[r][0][0] * dim);
        }
        double detre = A[0][0][0] * A[1][1][0] - A[0][0][1] * A[1][1][1]
                     - (A[0][1][0] * A[1][0][0] - A[0][1][1] * A[1][0][1]);
        double detim = A[0][0][0] * A[1][1][1] + A[0][0][1] * A[1][1][0]
                     - (A[0][1][0] * A[1][0][1] + A[0][1][1] * A[1][0][0]);
        double b0re, b0im, b1re, b1im;
        if (n2 == 0) { b0re = A[1][1][0]; b0im = A[1][1][1]; b1re = -A[1][0][0]; b1im = -A[1][0][1]; }
        else         { b0re = -A[0][1][0]; b0im = -A[0][1][1]; b1re = A[0][0][0]; b1im = A[0][0][1]; }
        double dmag = detre * detre + detim * detim;
        double t0re = (b0re * detre + b0im * detim) / dmag, t0im = (b0im * detre - b0re * detim) / dmag;
        double t1re = (b1re * detre + b1im * detim) / dmag, t1im = (b1im * detre - b1re * detim) / dmag;
        double pre = t0re * t1re + t0im * t1im, pim = t0re * t1im - t0im * t1re;
        double quad = d00 * (t0re * t0re + t0im * t0im) + d11 * (t1re * t1re + t1im * t1im)
                    + 2.0 * (dre * pre - dim * pim);
        double denom = sqrt(quad + (double)EPS);
        double w0re = t0re / denom, w0im = -t0im / denom;
        double w1re = t1re / denom, w1im = -t1im / denom;
        Wd[n2][0][0] = w0re; Wd[n2][0][1] = w0im;
        Wd[n2][1][0] = w1re; Wd[n2][1][1] = w1im;
        W2[i * 4 + n2 * 2 + 0] = make_float2((float)w0re, (float)w0im);
        W2[i * 4 + n2 * 2 + 1] = make_float2((float)w1re, (float)w1im);
      }
      if (DO_A) {
        sbc[0] = (float)(Wd[0][0][0] * Wd[0][0][0] + Wd[0][0][1] * Wd[0][0][1]);
        sbc[1] = (float)(Wd[0][1][0] * Wd[0][1][0] + Wd[0][1][1] * Wd[0][1][1]);
        sbc[2] = (float)(2.0 * (Wd[0][0][0] * Wd[0][1][0] + Wd[0][0][1] * Wd[0][1][1]));
        sbc[3] = (float)(-2.0 * (Wd[0][0][1] * Wd[0][1][0] - Wd[0][0][0] * Wd[0][1][1]));
        sbc[4] = (float)(Wd[1][0][0] * Wd[1][0][0] + Wd[1][0][1] * Wd[1][0][1]);
        sbc[5] = (float)(Wd[1][1][0] * Wd[1][1][0] + Wd[1][1][1] * Wd[1][1][1]);
        sbc[6] = (float)(2.0 * (Wd[1][0][0] * Wd[1][1][0] + Wd[1][0][1] * Wd[1][1][1]));
        sbc[7] = (float)(-2.0 * (Wd[1][0][1] * Wd[1][1][0] - Wd[1][0][0] * Wd[1][1][1]));
      }
    }
  } else {
    if (t == 0) {
      float2 w00 = W2[i * 4 + 0], w01 = W2[i * 4 + 1], w10 = W2[i * 4 + 2], w11 = W2[i * 4 + 3];
      sbc[0] = w00.x * w00.x + w00.y * w00.y;
      sbc[1] = w01.x * w01.x + w01.y * w01.y;
      sbc[2] = 2.f * (w00.x * w01.x + w00.y * w01.y);
      sbc[3] = -2.f * (w00.y * w01.x - w00.x * w01.y);
      sbc[4] = w10.x * w10.x + w10.y * w10.y;
      sbc[5] = w11.x * w11.x + w11.y * w11.y;
      sbc[6] = 2.f * (w10.x * w11.x + w10.y * w11.y);
      sbc[7] = -2.f * (w10.y * w11.x - w10.x * w11.y);
    }
  }

  if constexpr (DO_A) {
    __syncthreads();
    const float al0 = sbc[0], bt0 = sbc[1], gm0 = sbc[2], dl0 = sbc[3];
    const float al1 = sbc[4], bt1 = sbc[5], gm1 = sbc[6], dl1 = sbc[7];
    float nT0[K_] = {}, dT0[K_] = {}, nT1[K_] = {}, dT1[K_] = {};
    float2* y0r = YdR2 + (size_t)i * JH;
    float2* y1r = YdR2 + (size_t)(I_ + i) * JH;
#pragma unroll
    for (int l = 0; l < NPAIR; l++) {
      int j2 = t + l * 256;
      bool ok = j2 < JH;
      float a0a = al0 * q00[2 * l] + bt0 * q11[2 * l] + gm0 * qre[2 * l] + dl0 * qim[2 * l];
      float a0b = al0 * q00[2 * l + 1] + bt0 * q11[2 * l + 1] + gm0 * qre[2 * l + 1] + dl0 * qim[2 * l + 1];
      float a1a = al1 * q00[2 * l] + bt1 * q11[2 * l] + gm1 * qre[2 * l] + dl1 * qim[2 * l];
      float a1b = al1 * q00[2 * l + 1] + bt1 * q11[2 * l + 1] + gm1 * qre[2 * l + 1] + dl1 * qim[2 * l + 1];
      float r0a = R0[2 * l], r0b = R0[2 * l + 1], r1a = R1[2 * l], r1b = R1[2 * l + 1];
      float ydr0a = a0a / (r0a * r0a + EPS), ydr0b = a0b / (r0b * r0b + EPS);
      float ydr1a = a1a / (r1a * r1a + EPS), ydr1b = a1b / (r1b * r1b + EPS);
      float rd0a = 1.f / (r0a + EPS), rd0b = 1.f / (r0b + EPS);
      float rd1a = 1.f / (r1a + EPS), rd1b = 1.f / (r1b + EPS);
      if (ok) {
        y0r[j2] = make_float2(ydr0a, ydr0b);
        y1r[j2] = make_float2(ydr1a, ydr1b);
      }
#pragma unroll
      for (int k = 0; k < K_; k++) {
        float4 vp = ok ? V4[(size_t)k * JH + j2] : make_float4(0.f, 0.f, 0.f, 0.f);
        nT0[k] += ydr0a * vp.x + ydr0b * vp.z;
        dT0[k] += rd0a * vp.x + rd0b * vp.z;
        nT1[k] += ydr1a * vp.y + ydr1b * vp.w;
        dT1[k] += rd1a * vp.y + rd1b * vp.w;
      }
    }
#pragma unroll
    for (int k = 0; k < K_; k++) {
      float a = waveRed(nT0[k]); if (lane == 0) sred[wave][k] = a;
      float b = waveRed(dT0[k]); if (lane == 0) sred[wave][8 + k] = b;
      float c = waveRed(nT1[k]); if (lane == 0) sred[wave][16 + k] = c;
      float d = waveRed(dT1[k]); if (lane == 0) sred[wave][24 + k] = d;
    }
    __syncthreads();
    if (t < 32) sout[t] = sred[0][t] + sred[1][t] + sred[2][t] + sred[3][t];
    __syncthreads();
    if (t < 16) {
      int n = t >> 3, k = t & 7;
      float num = sout[n * 16 + k];
      float den = sout[n * 16 + 8 + k];
      float told = T[n * I_ * K_ + i * K_ + k];
      T[n * I_ * K_ + i * K_ + k] = told * sqrtf(num / (den + EPS));
    }
  }
}

// -------- pass B: partial I-reductions for the V update (deterministic) --------
__global__ __launch_bounds__(256) void k_passB(const float* __restrict__ T,
                                               const float2* __restrict__ V2,
                                               const float* __restrict__ YdR,
                                               float* __restrict__ partial, int iseg) {
  int t = threadIdx.x;
  int jt = blockIdx.x, s = blockIdx.y, n = blockIdx.z;
  int j = jt * TJ + t;
  bool ok = j < J_;
  float v[K_];
#pragma unroll
  for (int k = 0; k < K_; k++) {
    float2 p = ok ? V2[(size_t)k * J_ + j] : make_float2(0.f, 0.f);
    v[k] = (n == 0) ? p.x : p.y;
  }
  int i0 = s * iseg, i1 = min(i0 + iseg, I_);
  const float* yb = YdR + (size_t)n * I_ * J_;
  const float* Tb = T + (size_t)n * I_ * K_;
  float nV[K_] = {}, dV[K_] = {};
#pragma unroll 4
  for (int i = i0; i < i1; i++) {
    const float4* tp = (const float4*)(Tb + i * K_);
    float4 t03 = tp[0], t47 = tp[1];
    float Tn[K_] = {t03.x, t03.y, t03.z, t03.w, t47.x, t47.y, t47.z, t47.w};
    float ydr = ok ? yb[(size_t)i * J_ + j] : 0.f;
    float R = 0.f;
#pragma unroll
    for (int k = 0; k < K_; k++) R += Tn[k] * v[k];
    float rd2 = 1.f / (R + EPS);
#pragma unroll
    for (int k = 0; k < K_; k++) {
      nV[k] += Tn[k] * ydr;
      dV[k] += Tn[k] * rd2;
    }
  }
  if (ok) {
    size_t b0 = ((size_t)((s * 2 + n) * 2 + 0) * K_) * J_;
    size_t b1 = ((size_t)((s * 2 + n) * 2 + 1) * K_) * J_;
#pragma unroll
    for (int k = 0; k < K_; k++) partial[b0 + (size_t)k * J_ + j] = nV[k];
#pragma unroll
    for (int k = 0; k < K_; k++) partial[b1 + (size_t)k * J_ + j] = dV[k];
  }
}

// ---------------- finalize V ----------------
__global__ void k_finV(const float* __restrict__ partial, float2* V2, int nseg) {
  int idx = blockIdx.x * 256 + threadIdx.x;
  if (idx >= K_ * J_) return;
  int k = idx / J_, j = idx - k * J_;
  float res[2];
#pragma unroll
  for (int n = 0; n < 2; n++) {
    float num = 0.f, den = 0.f;
    for (int s = 0; s < nseg; s++) {
      num += partial[((size_t)((s * 2 + n) * 2 + 0) * K_ + k) * J_ + j];
      den += partial[((size_t)((s * 2 + n) * 2 + 1) * K_ + k) * J_ + j];
    }
    res[n] = sqrtf(num / (den + EPS));
  }
  float2 vo = V2[idx];
  V2[idx] = make_float2(vo.x * res[0], vo.y * res[1]);
}

// ---------------- final output: Y = W X, transposed to (N,J,I) ----------------
__global__ __launch_bounds__(256) void k_output(const float2* __restrict__ Xt,
                                                const float2* __restrict__ W2,
                                                float2* __restrict__ out) {
  __shared__ float2 tile[2][32][33];
  int i0 = blockIdx.x * 32, j0 = blockIdx.y * 32;
  int tx = threadIdx.x & 31, ty = threadIdx.x >> 5;
  for (int r = ty; r < 32; r += 8) {
    int i = i0 + r, j = j0 + tx;
    if (i < I_ && j < J_) {
      float2 w00 = W2[i * 4 + 0], w01 = W2[i * 4 + 1], w10 = W2[i * 4 + 2], w11 = W2[i * 4 + 3];
      float2 x0 = Xt[(size_t)i * J_ + j], x1 = Xt[((size_t)I_ + i) * J_ + j];
      tile[0][r][tx] = make_float2(w00.x * x0.x - w00.y * x0.y + w01.x * x1.x - w01.y * x1.y,
                                   w00.x * x0.y + w00.y * x0.x + w01.x * x1.y + w01.y * x1.x);
      tile[1][r][tx] = make_float2(w10.x * x0.x - w10.y * x0.y + w11.x * x1.x - w11.y * x1.y,
                                   w10.x * x0.y + w10.y * x0.x + w11.x * x1.y + w11.y * x1.x);
    }
  }
  __syncthreads();
  for (int r = ty; r < 32; r += 8) {
    int j = j0 + r, i = i0 + tx;
    if (i < I_ && j < J_) {
      out[((size_t)0 * J_ + j) * I_ + i] = tile[0][tx][r];
      out[((size_t)1 * J_ + j) * I_ + i] = tile[1][tx][r];
    }
  }
}

extern "C" void kernel_launch(void* const* d_in, const int* in_sizes, int n_in,
                              void* d_out, int out_size, void* d_ws, size_t ws_size,
                              hipStream_t stream) {
  const float* X = (const float*)d_in[0];
  const float* Tin = (const float*)d_in[1];
  const float* Vin = (const float*)d_in[2];

  char* ws = (char*)d_ws;
  size_t off = 0;
  auto alloc = [&](size_t bytes) {
    void* p = ws + off;
    off = (off + bytes + 255) & ~(size_t)255;
    return p;
  };
  float2* Xt = (float2*)alloc((size_t)2 * I_ * J_ * sizeof(float2));
  float* YdR = (float*)alloc((size_t)2 * I_ * J_ * sizeof(float));
  float2* V2 = (float2*)alloc((size_t)K_ * J_ * sizeof(float2));
  float* T = (float*)alloc((size_t)2 * I_ * K_ * sizeof(float));
  float2* W2 = (float2*)alloc((size_t)I_ * 4 * sizeof(float2));
  // partial: nseg chosen so we never exceed ws_size (32 segs if room, else 16)
  size_t partial32 = (size_t)32 * 2 * 2 * K_ * J_ * sizeof(float);
  int nseg = (off + partial32 <= ws_size) ? 32 : 16;
  float* partial = (float*)alloc((size_t)nseg * 2 * 2 * K_ * J_ * sizeof(float));
  int iseg = (I_ + nseg - 1) / nseg;
  (void)in_sizes; (void)n_in; (void)out_size;

  const float4* Xt4 = (const float4*)Xt;
  const float4* V4 = (const float4*)V2;
  float2* YdR2 = (float2*)YdR;

  k_init<<<(I_ * K_ * 2 + 255) / 256, 256, 0, stream>>>(Tin, Vin, T, V2, W2);
  dim3 tg((I_ + 31) / 32, (J_ + 31) / 32, 2);
  k_transpose<<<tg, 256, 0, stream>>>((const float2*)X, Xt);

  // A(0)
  k_CA<false, true><<<I_, 256, 0, stream>>>(Xt4, W2, T, V4, YdR2);
  for (int it = 0; it < NITER; it++) {
    k_passB<<<dim3(NJT, nseg, 2), TJ, 0, stream>>>(T, V2, YdR, partial, iseg);
    k_finV<<<(K_ * J_ + 255) / 256, 256, 0, stream>>>(partial, V2, nseg);
    if (it < NITER - 1) {
      // C(it) fused with A(it+1): X streamed once
      k_CA<true, true><<<I_, 256, 0, stream>>>(Xt4, W2, T, V4, YdR2);
    } else {
      // final C(29)
      k_CA<true, false><<<I_, 256, 0, stream>>>(Xt4, W2, T, V4, YdR2);
    }
  }
  dim3 og((I_ + 31) / 32, (J_ + 31) / 32);
  k_output<<<og, 256, 0, stream>>>(Xt, W2, (float2*)d_out);
}

// Round 3
// 4037.725 us; speedup vs baseline: 1.7833x; 1.7833x over previous
//
#include <hip/hip_runtime.h>

#define DEVINL __device__ __forceinline__

constexpr int J_ = 3000;   // frames
constexpr int I_ = 2049;   // freq bins
constexpr int K_ = 8;      // NMF bases
constexpr int NITER = 30;
constexpr float EPS = 1e-20f;  // NMF_EPS == IP_EPS
constexpr int JH = J_ / 2;     // 1500 complex-pairs (or j-pairs) per row
constexpr int TJB = 256;       // passB threads; each handles 2 j via float2
constexpr int NJT = (JH + TJB - 1) / TJB;  // 6

DEVINL float waveRed(float v) {
#pragma unroll
  for (int off = 32; off > 0; off >>= 1) v += __shfl_xor(v, off, 64);
  return v;
}

// ---------------- init: T -> (n,i,k) layout; V copy; W = identity ----------------
__global__ void k_init(const float* __restrict__ Tin, const float* __restrict__ Vin,
                       float* __restrict__ T, float2* __restrict__ V2, float2* __restrict__ W2) {
  int idx = blockIdx.x * 256 + threadIdx.x;
  if (idx < I_ * K_ * 2) {
    int n = idx & 1, rem = idx >> 1;  // idx = (i*K + k)*2 + n
    int k = rem & 7, i = rem >> 3;
    T[n * I_ * K_ + i * K_ + k] = Tin[idx];
  }
  if (idx < K_ * J_) V2[idx] = ((const float2*)Vin)[idx];
  if (idx < I_) {
    W2[idx * 4 + 0] = make_float2(1.f, 0.f);
    W2[idx * 4 + 1] = make_float2(0.f, 0.f);
    W2[idx * 4 + 2] = make_float2(0.f, 0.f);
    W2[idx * 4 + 3] = make_float2(1.f, 0.f);
  }
}

// ------------- transpose X (M,J,I) cplx -> Xt (M,I,J) cplx -------------
__global__ __launch_bounds__(256) void k_transpose(const float2* __restrict__ X, float2* __restrict__ Xt) {
  __shared__ float2 tile[32][33];
  int m = blockIdx.z;
  int i0 = blockIdx.x * 32, j0 = blockIdx.y * 32;
  int tx = threadIdx.x & 31, ty = threadIdx.x >> 5;
  for (int r = ty; r < 32; r += 8) {
    int j = j0 + r, i = i0 + tx;
    if (i < I_ && j < J_) tile[r][tx] = X[((size_t)m * J_ + j) * I_ + i];
  }
  __syncthreads();
  for (int r = ty; r < 32; r += 8) {
    int i = i0 + r, j = j0 + tx;
    if (i < I_ && j < J_) Xt[((size_t)m * I_ + i) * J_ + j] = tile[tx][r];
  }
}

// ============ fused kernel: [C(t): D + IP -> W_new] + [A(t+1): YdR + T update] ============
// Phase A re-reads X rows (L1/L2-hot after phase C) and V (L2-resident) and
// recomputes R — no cross-phase register caching, so VGPR stays <=128.
template <bool DO_C, bool DO_A>
__global__ __launch_bounds__(256, 4) void k_CA(const float4* __restrict__ Xt4,  // (2,I,JH)
                                               float2* __restrict__ W2,
                                               float* __restrict__ T,           // (2,I,K)
                                               const float4* __restrict__ V4,   // (K,JH)
                                               float2* __restrict__ YdR2) {     // (2,I,JH)
  const int i = blockIdx.x, t = threadIdx.x;
  const int wave = t >> 6, lane = t & 63;
  float T0[K_], T1[K_];
#pragma unroll
  for (int k = 0; k < K_; k++) {
    T0[k] = T[i * K_ + k];
    T1[k] = T[I_ * K_ + i * K_ + k];
  }
  const float4* x0r = Xt4 + (size_t)i * JH;
  const float4* x1r = Xt4 + (size_t)(I_ + i) * JH;

  __shared__ float sred[4][32];
  __shared__ float sout[32];
  __shared__ float sW[8];  // W_new for this i, as 8 floats

  if constexpr (DO_C) {
    float acc[8] = {};
#pragma unroll 2
    for (int j2 = t; j2 < JH; j2 += 256) {
      float4 x0 = x0r[j2], x1 = x1r[j2];
      float r0a = 0.f, r0b = 0.f, r1a = 0.f, r1b = 0.f;
#pragma unroll
      for (int k = 0; k < K_; k++) {
        float4 vp = V4[(size_t)k * JH + j2];
        r0a += T0[k] * vp.x; r1a += T1[k] * vp.y;
        r0b += T0[k] * vp.z; r1b += T1[k] * vp.w;
      }
      float i0a = 1.f / (r0a + EPS), i0b = 1.f / (r0b + EPS);
      float i1a = 1.f / (r1a + EPS), i1b = 1.f / (r1b + EPS);
      float n00a = x0.x * x0.x + x0.y * x0.y, n00b = x0.z * x0.z + x0.w * x0.w;
      float n11a = x1.x * x1.x + x1.y * x1.y, n11b = x1.z * x1.z + x1.w * x1.w;
      float crea = x0.x * x1.x + x0.y * x1.y, creb = x0.z * x1.z + x0.w * x1.w;
      float cima = x0.y * x1.x - x0.x * x1.y, cimb = x0.w * x1.z - x0.z * x1.w;
      acc[0] += n00a * i0a + n00b * i0b;
      acc[1] += n11a * i0a + n11b * i0b;
      acc[2] += crea * i0a + creb * i0b;
      acc[3] += cima * i0a + cimb * i0b;
      acc[4] += n00a * i1a + n00b * i1b;
      acc[5] += n11a * i1a + n11b * i1b;
      acc[6] += crea * i1a + creb * i1b;
      acc[7] += cima * i1a + cimb * i1b;
    }
#pragma unroll
    for (int q = 0; q < 8; q++) {
      float v = waveRed(acc[q]);
      if (lane == 0) sred[wave][q] = v;
    }
    __syncthreads();
    if (t < 8) sout[t] = sred[0][t] + sred[1][t] + sred[2][t] + sred[3][t];
    __syncthreads();
    if (t == 0) {
      const double Jinv = 1.0 / (double)J_;
      double D[2][4];
#pragma unroll
      for (int s2 = 0; s2 < 2; s2++) {
        D[s2][0] = (double)sout[s2 * 4 + 0] * Jinv + (double)EPS;
        D[s2][1] = (double)sout[s2 * 4 + 1] * Jinv + (double)EPS;
        D[s2][2] = (double)sout[s2 * 4 + 2] * Jinv;
        D[s2][3] = (double)sout[s2 * 4 + 3] * Jinv;
      }
      double Wd[2][2][2];
#pragma unroll
      for (int r = 0; r < 2; r++)
#pragma unroll
        for (int c = 0; c < 2; c++) {
          float2 w = W2[i * 4 + r * 2 + c];
          Wd[r][c][0] = w.x;
          Wd[r][c][1] = w.y;
        }
      for (int n2 = 0; n2 < 2; n2++) {
        double d00 = D[n2][0], d11 = D[n2][1], dre = D[n2][2], dim = D[n2][3];
        double A[2][2][2];
#pragma unroll
        for (int r = 0; r < 2; r++) {
          A[r][0][0] = Wd[r][0][0] * d00 + (Wd[r][1][0] * dre + Wd[r][1][1] * dim);
          A[r][0][1] = Wd[r][0][1] * d00 + (Wd[r][1][1] * dre - Wd[r][1][0] * dim);
          A[r][1][0] = Wd[r][1][0] * d11 + (Wd[r][0][0] * dre - Wd[r][0][1] * dim);
          A[r][1][1] = Wd[r][1][1] * d11 + (Wd[r][0][1] * dre + Wd[r][0][0] * dim);
        }
        double detre = A[0][0][0] * A[1][1][0] - A[0][0][1] * A[1][1][1]
                     - (A[0][1][0] * A[1][0][0] - A[0][1][1] * A[1][0][1]);
        double detim = A[0][0][0] * A[1][1][1] + A[0][0][1] * A[1][1][0]
                     - (A[0][1][0] * A[1][0][1] + A[0][1][1] * A[1][0][0]);
        double b0re, b0im, b1re, b1im;
        if (n2 == 0) { b0re = A[1][1][0]; b0im = A[1][1][1]; b1re = -A[1][0][0]; b1im = -A[1][0][1]; }
        else         { b0re = -A[0][1][0]; b0im = -A[0][1][1]; b1re = A[0][0][0]; b1im = A[0][0][1]; }
        double dmag = detre * detre + detim * detim;
        double t0re = (b0re * detre + b0im * detim) / dmag, t0im = (b0im * detre - b0re * detim) / dmag;
        double t1re = (b1re * detre + b1im * detim) / dmag, t1im = (b1im * detre - b1re * detim) / dmag;
        double pre = t0re * t1re + t0im * t1im, pim = t0re * t1im - t0im * t1re;
        double quad = d00 * (t0re * t0re + t0im * t0im) + d11 * (t1re * t1re + t1im * t1im)
                    + 2.0 * (dre * pre - dim * pim);
        double denom = sqrt(quad + (double)EPS);
        double w0re = t0re / denom, w0im = -t0im / denom;
        double w1re = t1re / denom, w1im = -t1im / denom;
        Wd[n2][0][0] = w0re; Wd[n2][0][1] = w0im;
        Wd[n2][1][0] = w1re; Wd[n2][1][1] = w1im;
        W2[i * 4 + n2 * 2 + 0] = make_float2((float)w0re, (float)w0im);
        W2[i * 4 + n2 * 2 + 1] = make_float2((float)w1re, (float)w1im);
      }
      sW[0] = (float)Wd[0][0][0]; sW[1] = (float)Wd[0][0][1];
      sW[2] = (float)Wd[0][1][0]; sW[3] = (float)Wd[0][1][1];
      sW[4] = (float)Wd[1][0][0]; sW[5] = (float)Wd[1][0][1];
      sW[6] = (float)Wd[1][1][0]; sW[7] = (float)Wd[1][1][1];
    }
  } else {
    if (t < 8) sW[t] = ((const float*)(W2 + (size_t)i * 4))[t];
  }

  if constexpr (DO_A) {
    __syncthreads();
    const float w00x = sW[0], w00y = sW[1], w01x = sW[2], w01y = sW[3];
    const float w10x = sW[4], w10y = sW[5], w11x = sW[6], w11y = sW[7];
    float nT0[K_] = {}, dT0[K_] = {}, nT1[K_] = {}, dT1[K_] = {};
    float2* y0r = YdR2 + (size_t)i * JH;
    float2* y1r = YdR2 + (size_t)(I_ + i) * JH;
#pragma unroll 1
    for (int j2 = t; j2 < JH; j2 += 256) {
      float4 x0 = x0r[j2], x1 = x1r[j2];
      float4 vp[K_];
      float r0a = 0.f, r0b = 0.f, r1a = 0.f, r1b = 0.f;
#pragma unroll
      for (int k = 0; k < K_; k++) {
        vp[k] = V4[(size_t)k * JH + j2];
        r0a += T0[k] * vp[k].x; r1a += T1[k] * vp[k].y;
        r0b += T0[k] * vp[k].z; r1b += T1[k] * vp[k].w;
      }
      float y0rea = w00x * x0.x - w00y * x0.y + w01x * x1.x - w01y * x1.y;
      float y0ima = w00x * x0.y + w00y * x0.x + w01x * x1.y + w01y * x1.x;
      float y1rea = w10x * x0.x - w10y * x0.y + w11x * x1.x - w11y * x1.y;
      float y1ima = w10x * x0.y + w10y * x0.x + w11x * x1.y + w11y * x1.x;
      float y0reb = w00x * x0.z - w00y * x0.w + w01x * x1.z - w01y * x1.w;
      float y0imb = w00x * x0.w + w00y * x0.z + w01x * x1.w + w01y * x1.z;
      float y1reb = w10x * x0.z - w10y * x0.w + w11x * x1.z - w11y * x1.w;
      float y1imb = w10x * x0.w + w10y * x0.z + w11x * x1.w + w11y * x1.z;
      float a0a = y0rea * y0rea + y0ima * y0ima, a0b = y0reb * y0reb + y0imb * y0imb;
      float a1a = y1rea * y1rea + y1ima * y1ima, a1b = y1reb * y1reb + y1imb * y1imb;
      float ydr0a = a0a / (r0a * r0a + EPS), ydr0b = a0b / (r0b * r0b + EPS);
      float ydr1a = a1a / (r1a * r1a + EPS), ydr1b = a1b / (r1b * r1b + EPS);
      float rd0a = 1.f / (r0a + EPS), rd0b = 1.f / (r0b + EPS);
      float rd1a = 1.f / (r1a + EPS), rd1b = 1.f / (r1b + EPS);
      y0r[j2] = make_float2(ydr0a, ydr0b);
      y1r[j2] = make_float2(ydr1a, ydr1b);
#pragma unroll
      for (int k = 0; k < K_; k++) {
        nT0[k] += ydr0a * vp[k].x + ydr0b * vp[k].z;
        dT0[k] += rd0a * vp[k].x + rd0b * vp[k].z;
        nT1[k] += ydr1a * vp[k].y + ydr1b * vp[k].w;
        dT1[k] += rd1a * vp[k].y + rd1b * vp[k].w;
      }
    }
#pragma unroll
    for (int k = 0; k < K_; k++) {
      float a = waveRed(nT0[k]); if (lane == 0) sred[wave][k] = a;
      float b = waveRed(dT0[k]); if (lane == 0) sred[wave][8 + k] = b;
      float c = waveRed(nT1[k]); if (lane == 0) sred[wave][16 + k] = c;
      float d = waveRed(dT1[k]); if (lane == 0) sred[wave][24 + k] = d;
    }
    __syncthreads();
    if (t < 32) sout[t] = sred[0][t] + sred[1][t] + sred[2][t] + sred[3][t];
    __syncthreads();
    if (t < 16) {
      int n = t >> 3, k = t & 7;
      float num = sout[n * 16 + k];
      float den = sout[n * 16 + 8 + k];
      float told = T[n * I_ * K_ + i * K_ + k];
      T[n * I_ * K_ + i * K_ + k] = told * sqrtf(num / (den + EPS));
    }
  }
}

// -------- pass B: partial I-reductions for the V update (2 j per thread, float2 loads) --------
__global__ __launch_bounds__(TJB, 4) void k_passB(const float* __restrict__ T,
                                                  const float4* __restrict__ V4,
                                                  const float2* __restrict__ YdR2,
                                                  float2* __restrict__ partial2, int iseg) {
  int t = threadIdx.x;
  int jt = blockIdx.x, s = blockIdx.y, n = blockIdx.z;
  int j2 = jt * TJB + t;  // pair index
  bool ok = j2 < JH;
  float va[K_], vb[K_];
#pragma unroll
  for (int k = 0; k < K_; k++) {
    float4 vp = ok ? V4[(size_t)k * JH + j2] : make_float4(0.f, 0.f, 0.f, 0.f);
    va[k] = (n == 0) ? vp.x : vp.y;
    vb[k] = (n == 0) ? vp.z : vp.w;
  }
  int i0 = s * iseg, i1 = min(i0 + iseg, I_);
  const float2* yb = YdR2 + (size_t)n * I_ * JH;
  const float* Tb = T + (size_t)n * I_ * K_;
  float nVa[K_] = {}, dVa[K_] = {}, nVb[K_] = {}, dVb[K_] = {};
#pragma unroll 2
  for (int i = i0; i < i1; i++) {
    const float4* tp = (const float4*)(Tb + i * K_);
    float4 t03 = tp[0], t47 = tp[1];
    float Tn[K_] = {t03.x, t03.y, t03.z, t03.w, t47.x, t47.y, t47.z, t47.w};
    float2 y = ok ? yb[(size_t)i * JH + j2] : make_float2(0.f, 0.f);
    float Ra = 0.f, Rb = 0.f;
#pragma unroll
    for (int k = 0; k < K_; k++) { Ra += Tn[k] * va[k]; Rb += Tn[k] * vb[k]; }
    float rda = 1.f / (Ra + EPS), rdb = 1.f / (Rb + EPS);
#pragma unroll
    for (int k = 0; k < K_; k++) {
      nVa[k] += Tn[k] * y.x; dVa[k] += Tn[k] * rda;
      nVb[k] += Tn[k] * y.y; dVb[k] += Tn[k] * rdb;
    }
  }
  if (ok) {
    size_t b0 = (size_t)((s * 2 + n) * 2 + 0) * K_ * JH;
    size_t b1 = (size_t)((s * 2 + n) * 2 + 1) * K_ * JH;
#pragma unroll
    for (int k = 0; k < K_; k++) {
      partial2[b0 + (size_t)k * JH + j2] = make_float2(nVa[k], nVb[k]);
      partial2[b1 + (size_t)k * JH + j2] = make_float2(dVa[k], dVb[k]);
    }
  }
}

// ---------------- finalize V ----------------
__global__ void k_finV(const float* __restrict__ partial, float2* V2, int nseg) {
  int idx = blockIdx.x * 256 + threadIdx.x;
  if (idx >= K_ * J_) return;
  int k = idx / J_, j = idx - k * J_;
  float res[2];
#pragma unroll
  for (int n = 0; n < 2; n++) {
    float num = 0.f, den = 0.f;
    for (int s = 0; s < nseg; s++) {
      num += partial[((size_t)((s * 2 + n) * 2 + 0) * K_ + k) * J_ + j];
      den += partial[((size_t)((s * 2 + n) * 2 + 1) * K_ + k) * J_ + j];
    }
    res[n] = sqrtf(num / (den + EPS));
  }
  float2 vo = V2[idx];
  V2[idx] = make_float2(vo.x * res[0], vo.y * res[1]);
}

// ---------------- final output: Y = W X, transposed to (N,J,I) ----------------
__global__ __launch_bounds__(256) void k_output(const float2* __restrict__ Xt,
                                                const float2* __restrict__ W2,
                                                float2* __restrict__ out) {
  __shared__ float2 tile[2][32][33];
  int i0 = blockIdx.x * 32, j0 = blockIdx.y * 32;
  int tx = threadIdx.x & 31, ty = threadIdx.x >> 5;
  for (int r = ty; r < 32; r += 8) {
    int i = i0 + r, j = j0 + tx;
    if (i < I_ && j < J_) {
      float2 w00 = W2[i * 4 + 0], w01 = W2[i * 4 + 1], w10 = W2[i * 4 + 2], w11 = W2[i * 4 + 3];
      float2 x0 = Xt[(size_t)i * J_ + j], x1 = Xt[((size_t)I_ + i) * J_ + j];
      tile[0][r][tx] = make_float2(w00.x * x0.x - w00.y * x0.y + w01.x * x1.x - w01.y * x1.y,
                                   w00.x * x0.y + w00.y * x0.x + w01.x * x1.y + w01.y * x1.x);
      tile[1][r][tx] = make_float2(w10.x * x0.x - w10.y * x0.y + w11.x * x1.x - w11.y * x1.y,
                                   w10.x * x0.y + w10.y * x0.x + w11.x * x1.y + w11.y * x1.x);
    }
  }
  __syncthreads();
  for (int r = ty; r < 32; r += 8) {
    int j = j0 + r, i = i0 + tx;
    if (i < I_ && j < J_) {
      out[((size_t)0 * J_ + j) * I_ + i] = tile[0][tx][r];
      out[((size_t)1 * J_ + j) * I_ + i] = tile[1][tx][r];
    }
  }
}

extern "C" void kernel_launch(void* const* d_in, const int* in_sizes, int n_in,
                              void* d_out, int out_size, void* d_ws, size_t ws_size,
                              hipStream_t stream) {
  const float* X = (const float*)d_in[0];
  const float* Tin = (const float*)d_in[1];
  const float* Vin = (const float*)d_in[2];

  char* ws = (char*)d_ws;
  size_t off = 0;
  auto alloc = [&](size_t bytes) {
    void* p = ws + off;
    off = (off + bytes + 255) & ~(size_t)255;
    return p;
  };
  float2* Xt = (float2*)alloc((size_t)2 * I_ * J_ * sizeof(float2));
  float2* YdR2 = (float2*)alloc((size_t)2 * I_ * JH * sizeof(float2));
  float2* V2 = (float2*)alloc((size_t)K_ * J_ * sizeof(float2));
  float* T = (float*)alloc((size_t)2 * I_ * K_ * sizeof(float));
  float2* W2 = (float2*)alloc((size_t)I_ * 4 * sizeof(float2));
  size_t partial32 = (size_t)32 * 2 * 2 * K_ * J_ * sizeof(float);
  int nseg = (off + partial32 <= ws_size) ? 32 : 16;
  float* partial = (float*)alloc((size_t)nseg * 2 * 2 * K_ * J_ * sizeof(float));
  int iseg = (I_ + nseg - 1) / nseg;
  (void)in_sizes; (void)n_in; (void)out_size;

  const float4* Xt4 = (const float4*)Xt;
  const float4* V4 = (const float4*)V2;

  k_init<<<(I_ * K_ * 2 + 255) / 256, 256, 0, stream>>>(Tin, Vin, T, V2, W2);
  dim3 tg((I_ + 31) / 32, (J_ + 31) / 32, 2);
  k_transpose<<<tg, 256, 0, stream>>>((const float2*)X, Xt);

  // A(0)
  k_CA<false, true><<<I_, 256, 0, stream>>>(Xt4, W2, T, V4, YdR2);
  for (int it = 0; it < NITER; it++) {
    k_passB<<<dim3(NJT, nseg, 2), TJB, 0, stream>>>(T, V4, YdR2, (float2*)partial, iseg);
    k_finV<<<(K_ * J_ + 255) / 256, 256, 0, stream>>>(partial, V2, nseg);
    if (it < NITER - 1) {
      k_CA<true, true><<<I_, 256, 0, stream>>>(Xt4, W2, T, V4, YdR2);
    } else {
      k_CA<true, false><<<I_, 256, 0, stream>>>(Xt4, W2, T, V4, YdR2);
    }
  }
  dim3 og((I_ + 31) / 32, (J_ + 31) / 32);
  k_output<<<og, 256, 0, stream>>>(Xt, W2, (float2*)d_out);
}

// Round 4
// 3323.328 us; speedup vs baseline: 2.1667x; 1.2150x over previous
//
#include <hip/hip_runtime.h>

#define DEVINL __device__ __forceinline__

constexpr int J_ = 3000;   // frames
constexpr int I_ = 2049;   // freq bins
constexpr int K_ = 8;      // NMF bases
constexpr int NITER = 30;
constexpr float EPS = 1e-20f;  // NMF_EPS == IP_EPS
constexpr int JH = 1500;       // real j-pairs per row
constexpr int JHP = 1536;      // padded j-pairs (6*256)
constexpr int JP = 2 * JHP;    // padded j count = 3072
constexpr int NL = JHP / 256;  // 6 uniform loop iterations
constexpr int TJB = 256;
constexpr int NJTP = JHP / TJB;  // 6

DEVINL float waveRed(float v) {
#pragma unroll
  for (int off = 32; off > 0; off >>= 1) v += __shfl_xor(v, off, 64);
  return v;
}

DEVINL float frcp(float x) { return __builtin_amdgcn_rcpf(x); }  // ~1 ulp

// ---------------- init: T -> (n,i,k); V copy (padded, zero-fill); W = identity ----------------
__global__ void k_init(const float* __restrict__ Tin, const float* __restrict__ Vin,
                       float* __restrict__ T, float2* __restrict__ V2, float2* __restrict__ W2) {
  int idx = blockIdx.x * 256 + threadIdx.x;
  if (idx < I_ * K_ * 2) {
    int n = idx & 1, rem = idx >> 1;  // idx = (i*K + k)*2 + n
    int k = rem & 7, i = rem >> 3;
    T[n * I_ * K_ + i * K_ + k] = Tin[idx];
  }
  if (idx < K_ * JP) {
    int k = idx / JP, j = idx - k * JP;
    float2 v = (j < J_) ? ((const float2*)Vin)[k * J_ + j] : make_float2(0.f, 0.f);
    V2[k * JP + j] = v;
  }
  if (idx < I_) {
    W2[idx * 4 + 0] = make_float2(1.f, 0.f);
    W2[idx * 4 + 1] = make_float2(0.f, 0.f);
    W2[idx * 4 + 2] = make_float2(0.f, 0.f);
    W2[idx * 4 + 3] = make_float2(1.f, 0.f);
  }
}

// ------- transpose X (M,J,I) cplx -> Xt (M,I,JP) cplx, zero-padding j in [J_,JP) -------
__global__ __launch_bounds__(256) void k_transpose(const float2* __restrict__ X, float2* __restrict__ Xt) {
  __shared__ float2 tile[32][33];
  int m = blockIdx.z;
  int i0 = blockIdx.x * 32, j0 = blockIdx.y * 32;
  int tx = threadIdx.x & 31, ty = threadIdx.x >> 5;
  for (int r = ty; r < 32; r += 8) {
    int j = j0 + r, i = i0 + tx;
    tile[r][tx] = (i < I_ && j < J_) ? X[((size_t)m * J_ + j) * I_ + i] : make_float2(0.f, 0.f);
  }
  __syncthreads();
  for (int r = ty; r < 32; r += 8) {
    int i = i0 + r, j = j0 + tx;
    if (i < I_) Xt[((size_t)m * I_ + i) * JP + j] = tile[tx][r];
  }
}

// ============ fused kernel: [C(t): D + IP -> W_new] + [A(t+1): YdR + T update] ============
template <bool DO_C, bool DO_A>
__global__ __launch_bounds__(256, 4) void k_CA(const float4* __restrict__ Xt4,  // (2,I,JHP)
                                               float2* __restrict__ W2,
                                               float* __restrict__ T,           // (2,I,K)
                                               const float4* __restrict__ V4,   // (K,JHP)
                                               float2* __restrict__ YdR2) {     // (2,I,JHP)
  const int i = blockIdx.x, t = threadIdx.x;
  const int wave = t >> 6, lane = t & 63;
  float T0[K_], T1[K_];
#pragma unroll
  for (int k = 0; k < K_; k++) {
    T0[k] = T[i * K_ + k];
    T1[k] = T[I_ * K_ + i * K_ + k];
  }
  const float4* x0r = Xt4 + (size_t)i * JHP;
  const float4* x1r = Xt4 + (size_t)(I_ + i) * JHP;

  __shared__ float sred[4][32];
  __shared__ float sout[32];
  __shared__ float sbc[8];  // alpha,beta,gamma,delta per source

  if constexpr (DO_C) {
    float acc[8] = {};
#pragma unroll 2
    for (int l = 0; l < NL; l++) {
      int j2 = t + l * 256;
      float4 x0 = x0r[j2], x1 = x1r[j2];
      float r0a = 0.f, r0b = 0.f, r1a = 0.f, r1b = 0.f;
#pragma unroll
      for (int k = 0; k < K_; k++) {
        float4 vp = V4[(size_t)k * JHP + j2];
        r0a += T0[k] * vp.x; r1a += T1[k] * vp.y;
        r0b += T0[k] * vp.z; r1b += T1[k] * vp.w;
      }
      float i0a = frcp(r0a + EPS), i0b = frcp(r0b + EPS);
      float i1a = frcp(r1a + EPS), i1b = frcp(r1b + EPS);
      float n00a = x0.x * x0.x + x0.y * x0.y, n00b = x0.z * x0.z + x0.w * x0.w;
      float n11a = x1.x * x1.x + x1.y * x1.y, n11b = x1.z * x1.z + x1.w * x1.w;
      float crea = x0.x * x1.x + x0.y * x1.y, creb = x0.z * x1.z + x0.w * x1.w;
      float cima = x0.y * x1.x - x0.x * x1.y, cimb = x0.w * x1.z - x0.z * x1.w;
      acc[0] += n00a * i0a + n00b * i0b;
      acc[1] += n11a * i0a + n11b * i0b;
      acc[2] += crea * i0a + creb * i0b;
      acc[3] += cima * i0a + cimb * i0b;
      acc[4] += n00a * i1a + n00b * i1b;
      acc[5] += n11a * i1a + n11b * i1b;
      acc[6] += crea * i1a + creb * i1b;
      acc[7] += cima * i1a + cimb * i1b;
    }
#pragma unroll
    for (int q = 0; q < 8; q++) {
      float v = waveRed(acc[q]);
      if (lane == 0) sred[wave][q] = v;
    }
    __syncthreads();
    if (t < 8) sout[t] = sred[0][t] + sred[1][t] + sred[2][t] + sred[3][t];
    __syncthreads();
    if (t == 0) {
      const double Jinv = 1.0 / (double)J_;
      double D[2][4];
#pragma unroll
      for (int s2 = 0; s2 < 2; s2++) {
        D[s2][0] = (double)sout[s2 * 4 + 0] * Jinv + (double)EPS;
        D[s2][1] = (double)sout[s2 * 4 + 1] * Jinv + (double)EPS;
        D[s2][2] = (double)sout[s2 * 4 + 2] * Jinv;
        D[s2][3] = (double)sout[s2 * 4 + 3] * Jinv;
      }
      double Wd[2][2][2];
#pragma unroll
      for (int r = 0; r < 2; r++)
#pragma unroll
        for (int c = 0; c < 2; c++) {
          float2 w = W2[i * 4 + r * 2 + c];
          Wd[r][c][0] = w.x;
          Wd[r][c][1] = w.y;
        }
      for (int n2 = 0; n2 < 2; n2++) {
        double d00 = D[n2][0], d11 = D[n2][1], dre = D[n2][2], dim = D[n2][3];
        double A[2][2][2];
#pragma unroll
        for (int r = 0; r < 2; r++) {
          A[r][0][0] = Wd[r][0][0] * d00 + (Wd[r][1][0] * dre + Wd[r][1][1] * dim);
          A[r][0][1] = Wd[r][0][1] * d00 + (Wd[r][1][1] * dre - Wd[r][1][0] * dim);
          A[r][1][0] = Wd[r][1][0] * d11 + (Wd[r][0][0] * dre - Wd[r][0][1] * dim);
          A[r][1][1] = Wd[r][1][1] * d11 + (Wd[r][0][1] * dre + Wd[r][0][0] * dim);
        }
        double detre = A[0][0][0] * A[1][1][0] - A[0][0][1] * A[1][1][1]
                     - (A[0][1][0] * A[1][0][0] - A[0][1][1] * A[1][0][1]);
        double detim = A[0][0][0] * A[1][1][1] + A[0][0][1] * A[1][1][0]
                     - (A[0][1][0] * A[1][0][1] + A[0][1][1] * A[1][0][0]);
        double b0re, b0im, b1re, b1im;
        if (n2 == 0) { b0re = A[1][1][0]; b0im = A[1][1][1]; b1re = -A[1][0][0]; b1im = -A[1][0][1]; }
        else         { b0re = -A[0][1][0]; b0im = -A[0][1][1]; b1re = A[0][0][0]; b1im = A[0][0][1]; }
        double dmag = detre * detre + detim * detim;
        double t0re = (b0re * detre + b0im * detim) / dmag, t0im = (b0im * detre - b0re * detim) / dmag;
        double t1re = (b1re * detre + b1im * detim) / dmag, t1im = (b1im * detre - b1re * detim) / dmag;
        double pre = t0re * t1re + t0im * t1im, pim = t0re * t1im - t0im * t1re;
        double quad = d00 * (t0re * t0re + t0im * t0im) + d11 * (t1re * t1re + t1im * t1im)
                    + 2.0 * (dre * pre - dim * pim);
        double denom = sqrt(quad + (double)EPS);
        double w0re = t0re / denom, w0im = -t0im / denom;
        double w1re = t1re / denom, w1im = -t1im / denom;
        Wd[n2][0][0] = w0re; Wd[n2][0][1] = w0im;
        Wd[n2][1][0] = w1re; Wd[n2][1][1] = w1im;
        W2[i * 4 + n2 * 2 + 0] = make_float2((float)w0re, (float)w0im);
        W2[i * 4 + n2 * 2 + 1] = make_float2((float)w1re, (float)w1im);
      }
      if (DO_A) {
        sbc[0] = (float)(Wd[0][0][0] * Wd[0][0][0] + Wd[0][0][1] * Wd[0][0][1]);
        sbc[1] = (float)(Wd[0][1][0] * Wd[0][1][0] + Wd[0][1][1] * Wd[0][1][1]);
        sbc[2] = (float)(2.0 * (Wd[0][0][0] * Wd[0][1][0] + Wd[0][0][1] * Wd[0][1][1]));
        sbc[3] = (float)(-2.0 * (Wd[0][0][1] * Wd[0][1][0] - Wd[0][0][0] * Wd[0][1][1]));
        sbc[4] = (float)(Wd[1][0][0] * Wd[1][0][0] + Wd[1][0][1] * Wd[1][0][1]);
        sbc[5] = (float)(Wd[1][1][0] * Wd[1][1][0] + Wd[1][1][1] * Wd[1][1][1]);
        sbc[6] = (float)(2.0 * (Wd[1][0][0] * Wd[1][1][0] + Wd[1][0][1] * Wd[1][1][1]));
        sbc[7] = (float)(-2.0 * (Wd[1][0][1] * Wd[1][1][0] - Wd[1][0][0] * Wd[1][1][1]));
      }
    }
  } else {
    if (t == 0) {
      float2 w00 = W2[i * 4 + 0], w01 = W2[i * 4 + 1], w10 = W2[i * 4 + 2], w11 = W2[i * 4 + 3];
      sbc[0] = w00.x * w00.x + w00.y * w00.y;
      sbc[1] = w01.x * w01.x + w01.y * w01.y;
      sbc[2] = 2.f * (w00.x * w01.x + w00.y * w01.y);
      sbc[3] = -2.f * (w00.y * w01.x - w00.x * w01.y);
      sbc[4] = w10.x * w10.x + w10.y * w10.y;
      sbc[5] = w11.x * w11.x + w11.y * w11.y;
      sbc[6] = 2.f * (w10.x * w11.x + w10.y * w11.y);
      sbc[7] = -2.f * (w10.y * w11.x - w10.x * w11.y);
    }
  }

  if constexpr (DO_A) {
    __syncthreads();
    const float al0 = sbc[0], bt0 = sbc[1], gm0 = sbc[2], dl0 = sbc[3];
    const float al1 = sbc[4], bt1 = sbc[5], gm1 = sbc[6], dl1 = sbc[7];
    float nT0[K_] = {}, dT0[K_] = {}, nT1[K_] = {}, dT1[K_] = {};
    float2* y0r = YdR2 + (size_t)i * JHP;
    float2* y1r = YdR2 + (size_t)(I_ + i) * JHP;
#pragma unroll 1
    for (int l = 0; l < NL; l++) {
      int j2 = t + l * 256;
      float4 x0 = x0r[j2], x1 = x1r[j2];
      float4 vp[K_];
      float r0a = 0.f, r0b = 0.f, r1a = 0.f, r1b = 0.f;
#pragma unroll
      for (int k = 0; k < K_; k++) {
        vp[k] = V4[(size_t)k * JHP + j2];
        r0a += T0[k] * vp[k].x; r1a += T1[k] * vp[k].y;
        r0b += T0[k] * vp[k].z; r1b += T1[k] * vp[k].w;
      }
      float n00a = x0.x * x0.x + x0.y * x0.y, n00b = x0.z * x0.z + x0.w * x0.w;
      float n11a = x1.x * x1.x + x1.y * x1.y, n11b = x1.z * x1.z + x1.w * x1.w;
      float crea = x0.x * x1.x + x0.y * x1.y, creb = x0.z * x1.z + x0.w * x1.w;
      float cima = x0.y * x1.x - x0.x * x1.y, cimb = x0.w * x1.z - x0.z * x1.w;
      float a0a = al0 * n00a + bt0 * n11a + gm0 * crea + dl0 * cima;
      float a0b = al0 * n00b + bt0 * n11b + gm0 * creb + dl0 * cimb;
      float a1a = al1 * n00a + bt1 * n11a + gm1 * crea + dl1 * cima;
      float a1b = al1 * n00b + bt1 * n11b + gm1 * creb + dl1 * cimb;
      float ydr0a = a0a * frcp(r0a * r0a + EPS), ydr0b = a0b * frcp(r0b * r0b + EPS);
      float ydr1a = a1a * frcp(r1a * r1a + EPS), ydr1b = a1b * frcp(r1b * r1b + EPS);
      float rd0a = frcp(r0a + EPS), rd0b = frcp(r0b + EPS);
      float rd1a = frcp(r1a + EPS), rd1b = frcp(r1b + EPS);
      y0r[j2] = make_float2(ydr0a, ydr0b);
      y1r[j2] = make_float2(ydr1a, ydr1b);
#pragma unroll
      for (int k = 0; k < K_; k++) {
        nT0[k] += ydr0a * vp[k].x + ydr0b * vp[k].z;
        dT0[k] += rd0a * vp[k].x + rd0b * vp[k].z;
        nT1[k] += ydr1a * vp[k].y + ydr1b * vp[k].w;
        dT1[k] += rd1a * vp[k].y + rd1b * vp[k].w;
      }
    }
#pragma unroll
    for (int k = 0; k < K_; k++) {
      float a = waveRed(nT0[k]); if (lane == 0) sred[wave][k] = a;
      float b = waveRed(dT0[k]); if (lane == 0) sred[wave][8 + k] = b;
      float c = waveRed(nT1[k]); if (lane == 0) sred[wave][16 + k] = c;
      float d = waveRed(dT1[k]); if (lane == 0) sred[wave][24 + k] = d;
    }
    __syncthreads();
    if (t < 32) sout[t] = sred[0][t] + sred[1][t] + sred[2][t] + sred[3][t];
    __syncthreads();
    if (t < 16) {
      int n = t >> 3, k = t & 7;
      float num = sout[n * 16 + k];
      float den = sout[n * 16 + 8 + k];
      float told = T[n * I_ * K_ + i * K_ + k];
      T[n * I_ * K_ + i * K_ + k] = told * sqrtf(num / (den + EPS));
    }
  }
}

// -------- pass B: partial I-reductions for the V update (2 j per thread, float2 loads) --------
__global__ __launch_bounds__(TJB, 4) void k_passB(const float* __restrict__ T,
                                                  const float4* __restrict__ V4,
                                                  const float2* __restrict__ YdR2,
                                                  float2* __restrict__ partial2, int iseg) {
  int t = threadIdx.x;
  int jt = blockIdx.x, s = blockIdx.y, n = blockIdx.z;
  int j2 = jt * TJB + t;  // pair index, < JHP (pads read zeros, writes guarded)
  float va[K_], vb[K_];
#pragma unroll
  for (int k = 0; k < K_; k++) {
    float4 vp = V4[(size_t)k * JHP + j2];
    va[k] = (n == 0) ? vp.x : vp.y;
    vb[k] = (n == 0) ? vp.z : vp.w;
  }
  int i0 = s * iseg, i1 = min(i0 + iseg, I_);
  const float2* yb = YdR2 + (size_t)n * I_ * JHP;
  const float* Tb = T + (size_t)n * I_ * K_;
  float nVa[K_] = {}, dVa[K_] = {}, nVb[K_] = {}, dVb[K_] = {};
#pragma unroll 4
  for (int i = i0; i < i1; i++) {
    const float4* tp = (const float4*)(Tb + i * K_);
    float4 t03 = tp[0], t47 = tp[1];
    float Tn[K_] = {t03.x, t03.y, t03.z, t03.w, t47.x, t47.y, t47.z, t47.w};
    float2 y = yb[(size_t)i * JHP + j2];
    float Ra = 0.f, Rb = 0.f;
#pragma unroll
    for (int k = 0; k < K_; k++) { Ra += Tn[k] * va[k]; Rb += Tn[k] * vb[k]; }
    float rda = frcp(Ra + EPS), rdb = frcp(Rb + EPS);
#pragma unroll
    for (int k = 0; k < K_; k++) {
      nVa[k] += Tn[k] * y.x; dVa[k] += Tn[k] * rda;
      nVb[k] += Tn[k] * y.y; dVb[k] += Tn[k] * rdb;
    }
  }
  if (j2 < JH) {
    size_t b0 = (size_t)((s * 2 + n) * 2 + 0) * K_ * JH;
    size_t b1 = (size_t)((s * 2 + n) * 2 + 1) * K_ * JH;
#pragma unroll
    for (int k = 0; k < K_; k++) {
      partial2[b0 + (size_t)k * JH + j2] = make_float2(nVa[k], nVb[k]);
      partial2[b1 + (size_t)k * JH + j2] = make_float2(dVa[k], dVb[k]);
    }
  }
}

// ---------------- finalize V: one thread per (n,k,j) ----------------
__global__ void k_finV(const float* __restrict__ partial, float* __restrict__ Vf, int nseg) {
  int idx = blockIdx.x * 256 + threadIdx.x;
  if (idx >= 2 * K_ * J_) return;
  int n = idx / (K_ * J_);
  int rem = idx - n * (K_ * J_);
  int k = rem / J_, j = rem - k * J_;
  float num = 0.f, den = 0.f;
  for (int s = 0; s < nseg; s++) {
    num += partial[((size_t)((s * 2 + n) * 2 + 0) * K_ + k) * J_ + j];
    den += partial[((size_t)((s * 2 + n) * 2 + 1) * K_ + k) * J_ + j];
  }
  float res = sqrtf(num / (den + EPS));
  Vf[((size_t)k * JP + j) * 2 + n] *= res;
}

// ---------------- final output: Y = W X, transposed to (N,J,I) ----------------
__global__ __launch_bounds__(256) void k_output(const float2* __restrict__ Xt,
                                                const float2* __restrict__ W2,
                                                float2* __restrict__ out) {
  __shared__ float2 tile[2][32][33];
  int i0 = blockIdx.x * 32, j0 = blockIdx.y * 32;
  int tx = threadIdx.x & 31, ty = threadIdx.x >> 5;
  for (int r = ty; r < 32; r += 8) {
    int i = i0 + r, j = j0 + tx;
    if (i < I_ && j < J_) {
      float2 w00 = W2[i * 4 + 0], w01 = W2[i * 4 + 1], w10 = W2[i * 4 + 2], w11 = W2[i * 4 + 3];
      float2 x0 = Xt[(size_t)i * JP + j], x1 = Xt[((size_t)I_ + i) * JP + j];
      tile[0][r][tx] = make_float2(w00.x * x0.x - w00.y * x0.y + w01.x * x1.x - w01.y * x1.y,
                                   w00.x * x0.y + w00.y * x0.x + w01.x * x1.y + w01.y * x1.x);
      tile[1][r][tx] = make_float2(w10.x * x0.x - w10.y * x0.y + w11.x * x1.x - w11.y * x1.y,
                                   w10.x * x0.y + w10.y * x0.x + w11.x * x1.y + w11.y * x1.x);
    }
  }
  __syncthreads();
  for (int r = ty; r < 32; r += 8) {
    int j = j0 + r, i = i0 + tx;
    if (i < I_ && j < J_) {
      out[((size_t)0 * J_ + j) * I_ + i] = tile[0][tx][r];
      out[((size_t)1 * J_ + j) * I_ + i] = tile[1][tx][r];
    }
  }
}

extern "C" void kernel_launch(void* const* d_in, const int* in_sizes, int n_in,
                              void* d_out, int out_size, void* d_ws, size_t ws_size,
                              hipStream_t stream) {
  const float* X = (const float*)d_in[0];
  const float* Tin = (const float*)d_in[1];
  const float* Vin = (const float*)d_in[2];

  char* ws = (char*)d_ws;
  size_t off = 0;
  auto alloc = [&](size_t bytes) {
    void* p = ws + off;
    off = (off + bytes + 255) & ~(size_t)255;
    return p;
  };
  float2* Xt = (float2*)alloc((size_t)2 * I_ * JP * sizeof(float2));
  float2* YdR2 = (float2*)alloc((size_t)2 * I_ * JHP * sizeof(float2));
  float2* V2 = (float2*)alloc((size_t)K_ * JP * sizeof(float2));
  float* T = (float*)alloc((size_t)2 * I_ * K_ * sizeof(float));
  float2* W2 = (float2*)alloc((size_t)I_ * 4 * sizeof(float2));
  size_t per_seg = (size_t)2 * 2 * K_ * J_ * sizeof(float);
  int nseg = (off + 64 * per_seg <= ws_size) ? 64 : ((off + 32 * per_seg <= ws_size) ? 32 : 16);
  float* partial = (float*)alloc((size_t)nseg * per_seg);
  int iseg = (I_ + nseg - 1) / nseg;
  (void)in_sizes; (void)n_in; (void)out_size;

  const float4* Xt4 = (const float4*)Xt;
  const float4* V4 = (const float4*)V2;

  k_init<<<(I_ * K_ * 2 + 255) / 256, 256, 0, stream>>>(Tin, Vin, T, V2, W2);
  dim3 tg((I_ + 31) / 32, JP / 32, 2);
  k_transpose<<<tg, 256, 0, stream>>>((const float2*)X, Xt);

  // A(0)
  k_CA<false, true><<<I_, 256, 0, stream>>>(Xt4, W2, T, V4, YdR2);
  for (int it = 0; it < NITER; it++) {
    k_passB<<<dim3(NJTP, nseg, 2), TJB, 0, stream>>>(T, V4, YdR2, (float2*)partial, iseg);
    k_finV<<<(2 * K_ * J_ + 255) / 256, 256, 0, stream>>>(partial, (float*)V2, nseg);
    if (it < NITER - 1) {
      k_CA<true, true><<<I_, 256, 0, stream>>>(Xt4, W2, T, V4, YdR2);
    } else {
      k_CA<true, false><<<I_, 256, 0, stream>>>(Xt4, W2, T, V4, YdR2);
    }
  }
  dim3 og((I_ + 31) / 32, (J_ + 31) / 32);
  k_output<<<og, 256, 0, stream>>>(Xt, W2, (float2*)d_out);
}

// Round 5
// 3105.107 us; speedup vs baseline: 2.3189x; 1.0703x over previous
//
#include <hip/hip_runtime.h>

#define DEVINL __device__ __forceinline__

constexpr int J_ = 3000;   // frames
constexpr int I_ = 2049;   // freq bins
constexpr int K_ = 8;      // NMF bases
constexpr int NITER = 30;
constexpr float EPS = 1e-20f;  // NMF_EPS == IP_EPS
constexpr int JH = 1500;       // real j-pairs per row
constexpr int JHP = 1536;      // padded j-pairs (6*256)
constexpr int JP = 2 * JHP;    // padded j count = 3072
constexpr int NL = JHP / 256;  // 6 uniform loop iterations
constexpr int TJB = 256;
constexpr int NJTP = JHP / TJB;  // 6

typedef float f32x2 __attribute__((ext_vector_type(2)));

DEVINL float waveRed(float v) {
#pragma unroll
  for (int off = 32; off > 0; off >>= 1) v += __shfl_xor(v, off, 64);
  return v;
}

DEVINL float frcp(float x) { return __builtin_amdgcn_rcpf(x); }  // ~1 ulp
DEVINL f32x2 sp(float s) { return (f32x2){s, s}; }
DEVINL f32x2 xy(float4 v) { return (f32x2){v.x, v.y}; }
DEVINL f32x2 zw(float4 v) { return (f32x2){v.z, v.w}; }

// ---------------- init: T -> (n,i,k); V copy (padded, zero-fill); W = identity ----------------
__global__ void k_init(const float* __restrict__ Tin, const float* __restrict__ Vin,
                       float* __restrict__ T, float2* __restrict__ V2, float2* __restrict__ W2) {
  int idx = blockIdx.x * 256 + threadIdx.x;
  if (idx < I_ * K_ * 2) {
    int n = idx & 1, rem = idx >> 1;  // idx = (i*K + k)*2 + n
    int k = rem & 7, i = rem >> 3;
    T[n * I_ * K_ + i * K_ + k] = Tin[idx];
  }
  if (idx < K_ * JP) {
    int k = idx / JP, j = idx - k * JP;
    float2 v = (j < J_) ? ((const float2*)Vin)[k * J_ + j] : make_float2(0.f, 0.f);
    V2[k * JP + j] = v;
  }
  if (idx < I_) {
    W2[idx * 4 + 0] = make_float2(1.f, 0.f);
    W2[idx * 4 + 1] = make_float2(0.f, 0.f);
    W2[idx * 4 + 2] = make_float2(0.f, 0.f);
    W2[idx * 4 + 3] = make_float2(1.f, 0.f);
  }
}

// ------- transpose X (M,J,I) cplx -> Xt (M,I,JP) cplx, zero-padding j in [J_,JP) -------
__global__ __launch_bounds__(256) void k_transpose(const float2* __restrict__ X, float2* __restrict__ Xt) {
  __shared__ float2 tile[32][33];
  int m = blockIdx.z;
  int i0 = blockIdx.x * 32, j0 = blockIdx.y * 32;
  int tx = threadIdx.x & 31, ty = threadIdx.x >> 5;
  for (int r = ty; r < 32; r += 8) {
    int j = j0 + r, i = i0 + tx;
    tile[r][tx] = (i < I_ && j < J_) ? X[((size_t)m * J_ + j) * I_ + i] : make_float2(0.f, 0.f);
  }
  __syncthreads();
  for (int r = ty; r < 32; r += 8) {
    int i = i0 + r, j = j0 + tx;
    if (i < I_) Xt[((size_t)m * I_ + i) * JP + j] = tile[tx][r];
  }
}

// ============ fused kernel: [C(t): D + IP -> W_new] + [A(t+1): YdR + T update] ============
// Source-packed f32x2 math: {src0, src1} pairs ride v_pk_fma_f32; registers flat vs scalar.
template <bool DO_C, bool DO_A>
__global__ __launch_bounds__(256, 4) void k_CA(const float4* __restrict__ Xt4,  // (2,I,JHP)
                                               float2* __restrict__ W2,
                                               float* __restrict__ T,           // (2,I,K)
                                               const float4* __restrict__ V4,   // (K,JHP) {v0a,v1a,v0b,v1b}
                                               float2* __restrict__ YdR2) {     // (2,I,JHP)
  const int i = blockIdx.x, t = threadIdx.x;
  const int wave = t >> 6, lane = t & 63;
  f32x2 Tp[K_];  // {T0[k], T1[k]}
#pragma unroll
  for (int k = 0; k < K_; k++) {
    Tp[k] = (f32x2){T[i * K_ + k], T[I_ * K_ + i * K_ + k]};
  }
  const float4* x0r = Xt4 + (size_t)i * JHP;
  const float4* x1r = Xt4 + (size_t)(I_ + i) * JHP;

  __shared__ float sred[4][32];
  __shared__ float sout[32];
  __shared__ float sbc[8];  // alpha,beta,gamma,delta per source

  if constexpr (DO_C) {
    f32x2 an00 = sp(0.f), an11 = sp(0.f), acre = sp(0.f), acim = sp(0.f);  // {src0,src1}
#pragma unroll 2
    for (int l = 0; l < NL; l++) {
      int j2 = t + l * 256;
      float4 x0 = x0r[j2], x1 = x1r[j2];
      f32x2 rA = sp(0.f), rB = sp(0.f);
#pragma unroll
      for (int k = 0; k < K_; k++) {
        float4 vp = V4[(size_t)k * JHP + j2];
        rA += Tp[k] * xy(vp);
        rB += Tp[k] * zw(vp);
      }
      f32x2 iA = (f32x2){frcp(rA.x + EPS), frcp(rA.y + EPS)};
      f32x2 iB = (f32x2){frcp(rB.x + EPS), frcp(rB.y + EPS)};
      float n00a = x0.x * x0.x + x0.y * x0.y, n00b = x0.z * x0.z + x0.w * x0.w;
      float n11a = x1.x * x1.x + x1.y * x1.y, n11b = x1.z * x1.z + x1.w * x1.w;
      float crea = x0.x * x1.x + x0.y * x1.y, creb = x0.z * x1.z + x0.w * x1.w;
      float cima = x0.y * x1.x - x0.x * x1.y, cimb = x0.w * x1.z - x0.z * x1.w;
      an00 += sp(n00a) * iA + sp(n00b) * iB;
      an11 += sp(n11a) * iA + sp(n11b) * iB;
      acre += sp(crea) * iA + sp(creb) * iB;
      acim += sp(cima) * iA + sp(cimb) * iB;
    }
    float vals[8] = {an00.x, an11.x, acre.x, acim.x, an00.y, an11.y, acre.y, acim.y};
#pragma unroll
    for (int q = 0; q < 8; q++) {
      float v = waveRed(vals[q]);
      if (lane == 0) sred[wave][q] = v;
    }
    __syncthreads();
    if (t < 8) sout[t] = sred[0][t] + sred[1][t] + sred[2][t] + sred[3][t];
    __syncthreads();
    if (t == 0) {
      const double Jinv = 1.0 / (double)J_;
      double D[2][4];
#pragma unroll
      for (int s2 = 0; s2 < 2; s2++) {
        D[s2][0] = (double)sout[s2 * 4 + 0] * Jinv + (double)EPS;
        D[s2][1] = (double)sout[s2 * 4 + 1] * Jinv + (double)EPS;
        D[s2][2] = (double)sout[s2 * 4 + 2] * Jinv;
        D[s2][3] = (double)sout[s2 * 4 + 3] * Jinv;
      }
      double Wd[2][2][2];
#pragma unroll
      for (int r = 0; r < 2; r++)
#pragma unroll
        for (int c = 0; c < 2; c++) {
          float2 w = W2[i * 4 + r * 2 + c];
          Wd[r][c][0] = w.x;
          Wd[r][c][1] = w.y;
        }
      for (int n2 = 0; n2 < 2; n2++) {
        double d00 = D[n2][0], d11 = D[n2][1], dre = D[n2][2], dim = D[n2][3];
        double A[2][2][2];
#pragma unroll
        for (int r = 0; r < 2; r++) {
          A[r][0][0] = Wd[r][0][0] * d00 + (Wd[r][1][0] * dre + Wd[r][1][1] * dim);
          A[r][0][1] = Wd[r][0][1] * d00 + (Wd[r][1][1] * dre - Wd[r][1][0] * dim);
          A[r][1][0] = Wd[r][1][0] * d11 + (Wd[r][0][0] * dre - Wd[r][0][1] * dim);
          A[r][1][1] = Wd[r][1][1] * d11 + (Wd[r][0][1] * dre + Wd[r][0][0] * dim);
        }
        double detre = A[0][0][0] * A[1][1][0] - A[0][0][1] * A[1][1][1]
                     - (A[0][1][0] * A[1][0][0] - A[0][1][1] * A[1][0][1]);
        double detim = A[0][0][0] * A[1][1][1] + A[0][0][1] * A[1][1][0]
                     - (A[0][1][0] * A[1][0][1] + A[0][1][1] * A[1][0][0]);
        double b0re, b0im, b1re, b1im;
        if (n2 == 0) { b0re = A[1][1][0]; b0im = A[1][1][1]; b1re = -A[1][0][0]; b1im = -A[1][0][1]; }
        else         { b0re = -A[0][1][0]; b0im = -A[0][1][1]; b1re = A[0][0][0]; b1im = A[0][0][1]; }
        double dmag = detre * detre + detim * detim;
        double t0re = (b0re * detre + b0im * detim) / dmag, t0im = (b0im * detre - b0re * detim) / dmag;
        double t1re = (b1re * detre + b1im * detim) / dmag, t1im = (b1im * detre - b1re * detim) / dmag;
        double pre = t0re * t1re + t0im * t1im, pim = t0re * t1im - t0im * t1re;
        double quad = d00 * (t0re * t0re + t0im * t0im) + d11 * (t1re * t1re + t1im * t1im)
                    + 2.0 * (dre * pre - dim * pim);
        double denom = sqrt(quad + (double)EPS);
        double w0re = t0re / denom, w0im = -t0im / denom;
        double w1re = t1re / denom, w1im = -t1im / denom;
        Wd[n2][0][0] = w0re; Wd[n2][0][1] = w0im;
        Wd[n2][1][0] = w1re; Wd[n2][1][1] = w1im;
        W2[i * 4 + n2 * 2 + 0] = make_float2((float)w0re, (float)w0im);
        W2[i * 4 + n2 * 2 + 1] = make_float2((float)w1re, (float)w1im);
      }
      if (DO_A) {
        sbc[0] = (float)(Wd[0][0][0] * Wd[0][0][0] + Wd[0][0][1] * Wd[0][0][1]);
        sbc[1] = (float)(Wd[0][1][0] * Wd[0][1][0] + Wd[0][1][1] * Wd[0][1][1]);
        sbc[2] = (float)(2.0 * (Wd[0][0][0] * Wd[0][1][0] + Wd[0][0][1] * Wd[0][1][1]));
        sbc[3] = (float)(-2.0 * (Wd[0][0][1] * Wd[0][1][0] - Wd[0][0][0] * Wd[0][1][1]));
        sbc[4] = (float)(Wd[1][0][0] * Wd[1][0][0] + Wd[1][0][1] * Wd[1][0][1]);
        sbc[5] = (float)(Wd[1][1][0] * Wd[1][1][0] + Wd[1][1][1] * Wd[1][1][1]);
        sbc[6] = (float)(2.0 * (Wd[1][0][0] * Wd[1][1][0] + Wd[1][0][1] * Wd[1][1][1]));
        sbc[7] = (float)(-2.0 * (Wd[1][0][1] * Wd[1][1][0] - Wd[1][0][0] * Wd[1][1][1]));
      }
    }
  } else {
    if (t == 0) {
      float2 w00 = W2[i * 4 + 0], w01 = W2[i * 4 + 1], w10 = W2[i * 4 + 2], w11 = W2[i * 4 + 3];
      sbc[0] = w00.x * w00.x + w00.y * w00.y;
      sbc[1] = w01.x * w01.x + w01.y * w01.y;
      sbc[2] = 2.f * (w00.x * w01.x + w00.y * w01.y);
      sbc[3] = -2.f * (w00.y * w01.x - w00.x * w01.y);
      sbc[4] = w10.x * w10.x + w10.y * w10.y;
      sbc[5] = w11.x * w11.x + w11.y * w11.y;
      sbc[6] = 2.f * (w10.x * w11.x + w10.y * w11.y);
      sbc[7] = -2.f * (w10.y * w11.x - w10.x * w11.y);
    }
  }

  if constexpr (DO_A) {
    __syncthreads();
    const f32x2 alp = (f32x2){sbc[0], sbc[4]}, btp = (f32x2){sbc[1], sbc[5]};
    const f32x2 gmp = (f32x2){sbc[2], sbc[6]}, dlp = (f32x2){sbc[3], sbc[7]};
    f32x2 nT[K_], dT[K_];  // {src0, src1} each
#pragma unroll
    for (int k = 0; k < K_; k++) { nT[k] = sp(0.f); dT[k] = sp(0.f); }
    float2* y0r = YdR2 + (size_t)i * JHP;
    float2* y1r = YdR2 + (size_t)(I_ + i) * JHP;
#pragma unroll 1
    for (int l = 0; l < NL; l++) {
      int j2 = t + l * 256;
      float4 x0 = x0r[j2], x1 = x1r[j2];
      float4 vp[K_];
      f32x2 rA = sp(0.f), rB = sp(0.f);
#pragma unroll
      for (int k = 0; k < K_; k++) {
        vp[k] = V4[(size_t)k * JHP + j2];
        rA += Tp[k] * xy(vp[k]);
        rB += Tp[k] * zw(vp[k]);
      }
      float n00a = x0.x * x0.x + x0.y * x0.y, n00b = x0.z * x0.z + x0.w * x0.w;
      float n11a = x1.x * x1.x + x1.y * x1.y, n11b = x1.z * x1.z + x1.w * x1.w;
      float crea = x0.x * x1.x + x0.y * x1.y, creb = x0.z * x1.z + x0.w * x1.w;
      float cima = x0.y * x1.x - x0.x * x1.y, cimb = x0.w * x1.z - x0.z * x1.w;
      f32x2 aA = alp * n00a + btp * n11a + gmp * crea + dlp * cima;
      f32x2 aB = alp * n00b + btp * n11b + gmp * creb + dlp * cimb;
      f32x2 ydrA = aA * (f32x2){frcp(rA.x * rA.x + EPS), frcp(rA.y * rA.y + EPS)};
      f32x2 ydrB = aB * (f32x2){frcp(rB.x * rB.x + EPS), frcp(rB.y * rB.y + EPS)};
      f32x2 rdA = (f32x2){frcp(rA.x + EPS), frcp(rA.y + EPS)};
      f32x2 rdB = (f32x2){frcp(rB.x + EPS), frcp(rB.y + EPS)};
      y0r[j2] = make_float2(ydrA.x, ydrB.x);
      y1r[j2] = make_float2(ydrA.y, ydrB.y);
#pragma unroll
      for (int k = 0; k < K_; k++) {
        nT[k] += ydrA * xy(vp[k]) + ydrB * zw(vp[k]);
        dT[k] += rdA * xy(vp[k]) + rdB * zw(vp[k]);
      }
    }
#pragma unroll
    for (int k = 0; k < K_; k++) {
      float a = waveRed(nT[k].x); if (lane == 0) sred[wave][k] = a;
      float b = waveRed(dT[k].x); if (lane == 0) sred[wave][8 + k] = b;
      float c = waveRed(nT[k].y); if (lane == 0) sred[wave][16 + k] = c;
      float d = waveRed(dT[k].y); if (lane == 0) sred[wave][24 + k] = d;
    }
    __syncthreads();
    if (t < 32) sout[t] = sred[0][t] + sred[1][t] + sred[2][t] + sred[3][t];
    __syncthreads();
    if (t < 16) {
      int n = t >> 3, k = t & 7;
      float num = sout[n * 16 + k];
      float den = sout[n * 16 + 8 + k];
      float told = T[n * I_ * K_ + i * K_ + k];
      T[n * I_ * K_ + i * K_ + k] = told * sqrtf(num / (den + EPS));
    }
  }
}

// -------- pass B: partial I-reductions for the V update (j-pair packed f32x2) --------
__global__ __launch_bounds__(TJB, 4) void k_passB(const float* __restrict__ T,
                                                  const float4* __restrict__ V4,
                                                  const float2* __restrict__ YdR2,
                                                  float2* __restrict__ partial2, int iseg) {
  int t = threadIdx.x;
  int jt = blockIdx.x, s = blockIdx.y, n = blockIdx.z;
  int j2 = jt * TJB + t;  // pair index, < JHP (pads read zeros, writes guarded)
  f32x2 va2[K_];          // {v(2j), v(2j+1)} of this source
#pragma unroll
  for (int k = 0; k < K_; k++) {
    float4 vp = V4[(size_t)k * JHP + j2];
    va2[k] = (n == 0) ? (f32x2){vp.x, vp.z} : (f32x2){vp.y, vp.w};
  }
  int i0 = s * iseg, i1 = min(i0 + iseg, I_);
  const float2* yb = YdR2 + (size_t)n * I_ * JHP;
  const float* Tb = T + (size_t)n * I_ * K_;
  f32x2 nV[K_], dV[K_];
#pragma unroll
  for (int k = 0; k < K_; k++) { nV[k] = sp(0.f); dV[k] = sp(0.f); }
#pragma unroll 4
  for (int i = i0; i < i1; i++) {
    const float4* tp = (const float4*)(Tb + i * K_);
    float4 t03 = tp[0], t47 = tp[1];
    float Tn[K_] = {t03.x, t03.y, t03.z, t03.w, t47.x, t47.y, t47.z, t47.w};
    float2 yl = yb[(size_t)i * JHP + j2];
    f32x2 y = (f32x2){yl.x, yl.y};
    f32x2 R = sp(0.f);
#pragma unroll
    for (int k = 0; k < K_; k++) R += sp(Tn[k]) * va2[k];
    f32x2 rd = (f32x2){frcp(R.x + EPS), frcp(R.y + EPS)};
#pragma unroll
    for (int k = 0; k < K_; k++) {
      nV[k] += sp(Tn[k]) * y;
      dV[k] += sp(Tn[k]) * rd;
    }
  }
  if (j2 < JH) {
    size_t b0 = (size_t)((s * 2 + n) * 2 + 0) * K_ * JH;
    size_t b1 = (size_t)((s * 2 + n) * 2 + 1) * K_ * JH;
#pragma unroll
    for (int k = 0; k < K_; k++) {
      partial2[b0 + (size_t)k * JH + j2] = make_float2(nV[k].x, nV[k].y);
      partial2[b1 + (size_t)k * JH + j2] = make_float2(dV[k].x, dV[k].y);
    }
  }
}

// ---------------- finalize V: one thread per (n,k,j) ----------------
__global__ void k_finV(const float* __restrict__ partial, float* __restrict__ Vf, int nseg) {
  int idx = blockIdx.x * 256 + threadIdx.x;
  if (idx >= 2 * K_ * J_) return;
  int n = idx / (K_ * J_);
  int rem = idx - n * (K_ * J_);
  int k = rem / J_, j = rem - k * J_;
  float num = 0.f, den = 0.f;
  for (int s = 0; s < nseg; s++) {
    num += partial[((size_t)((s * 2 + n) * 2 + 0) * K_ + k) * J_ + j];
    den += partial[((size_t)((s * 2 + n) * 2 + 1) * K_ + k) * J_ + j];
  }
  float res = sqrtf(num / (den + EPS));
  Vf[((size_t)k * JP + j) * 2 + n] *= res;
}

// ---------------- final output: Y = W X, transposed to (N,J,I) ----------------
__global__ __launch_bounds__(256) void k_output(const float2* __restrict__ Xt,
                                                const float2* __restrict__ W2,
                                                float2* __restrict__ out) {
  __shared__ float2 tile[2][32][33];
  int i0 = blockIdx.x * 32, j0 = blockIdx.y * 32;
  int tx = threadIdx.x & 31, ty = threadIdx.x >> 5;
  for (int r = ty; r < 32; r += 8) {
    int i = i0 + r, j = j0 + tx;
    if (i < I_ && j < J_) {
      float2 w00 = W2[i * 4 + 0], w01 = W2[i * 4 + 1], w10 = W2[i * 4 + 2], w11 = W2[i * 4 + 3];
      float2 x0 = Xt[(size_t)i * JP + j], x1 = Xt[((size_t)I_ + i) * JP + j];
      tile[0][r][tx] = make_float2(w00.x * x0.x - w00.y * x0.y + w01.x * x1.x - w01.y * x1.y,
                                   w00.x * x0.y + w00.y * x0.x + w01.x * x1.y + w01.y * x1.x);
      tile[1][r][tx] = make_float2(w10.x * x0.x - w10.y * x0.y + w11.x * x1.x - w11.y * x1.y,
                                   w10.x * x0.y + w10.y * x0.x + w11.x * x1.y + w11.y * x1.x);
    }
  }
  __syncthreads();
  for (int r = ty; r < 32; r += 8) {
    int j = j0 + r, i = i0 + tx;
    if (i < I_ && j < J_) {
      out[((size_t)0 * J_ + j) * I_ + i] = tile[0][tx][r];
      out[((size_t)1 * J_ + j) * I_ + i] = tile[1][tx][r];
    }
  }
}

extern "C" void kernel_launch(void* const* d_in, const int* in_sizes, int n_in,
                              void* d_out, int out_size, void* d_ws, size_t ws_size,
                              hipStream_t stream) {
  const float* X = (const float*)d_in[0];
  const float* Tin = (const float*)d_in[1];
  const float* Vin = (const float*)d_in[2];

  char* ws = (char*)d_ws;
  size_t off = 0;
  auto alloc = [&](size_t bytes) {
    void* p = ws + off;
    off = (off + bytes + 255) & ~(size_t)255;
    return p;
  };
  float2* Xt = (float2*)alloc((size_t)2 * I_ * JP * sizeof(float2));
  float2* YdR2 = (float2*)alloc((size_t)2 * I_ * JHP * sizeof(float2));
  float2* V2 = (float2*)alloc((size_t)K_ * JP * sizeof(float2));
  float* T = (float*)alloc((size_t)2 * I_ * K_ * sizeof(float));
  float2* W2 = (float2*)alloc((size_t)I_ * 4 * sizeof(float2));
  size_t per_seg = (size_t)2 * 2 * K_ * J_ * sizeof(float);
  int nseg = (off + 64 * per_seg <= ws_size) ? 64 : ((off + 32 * per_seg <= ws_size) ? 32 : 16);
  float* partial = (float*)alloc((size_t)nseg * per_seg);
  int iseg = (I_ + nseg - 1) / nseg;
  (void)in_sizes; (void)n_in; (void)out_size;

  const float4* Xt4 = (const float4*)Xt;
  const float4* V4 = (const float4*)V2;

  k_init<<<(I_ * K_ * 2 + 255) / 256, 256, 0, stream>>>(Tin, Vin, T, V2, W2);
  dim3 tg((I_ + 31) / 32, JP / 32, 2);
  k_transpose<<<tg, 256, 0, stream>>>((const float2*)X, Xt);

  // A(0)
  k_CA<false, true><<<I_, 256, 0, stream>>>(Xt4, W2, T, V4, YdR2);
  for (int it = 0; it < NITER; it++) {
    k_passB<<<dim3(NJTP, nseg, 2), TJB, 0, stream>>>(T, V4, YdR2, (float2*)partial, iseg);
    k_finV<<<(2 * K_ * J_ + 255) / 256, 256, 0, stream>>>(partial, (float*)V2, nseg);
    if (it < NITER - 1) {
      k_CA<true, true><<<I_, 256, 0, stream>>>(Xt4, W2, T, V4, YdR2);
    } else {
      k_CA<true, false><<<I_, 256, 0, stream>>>(Xt4, W2, T, V4, YdR2);
    }
  }
  dim3 og((I_ + 31) / 32, (J_ + 31) / 32);
  k_output<<<og, 256, 0, stream>>>(Xt, W2, (float2*)d_out);
}